// Round 10
// baseline (526.655 us; speedup 1.0000x reference)
//
#include <hip/hip_runtime.h>

#define N_ENT 50000
#define N_REL 500
#define N_EDGE 500000
#define HEADS 2
#define DIM 64
#define POW_ITER 3
#define ALPHA 0.15f
#define LN_EPS 1e-5f
#define NBLK 49  // ceil(N_ENT/1024)

typedef unsigned uv4 __attribute__((ext_vector_type(4)));

// bf16 round-to-nearest-even pack
static __device__ __forceinline__ unsigned bf16_rne(float f) {
  unsigned u = __float_as_uint(f);
  return (u + 0x7FFFu + ((u >> 16) & 1u)) >> 16;
}

// ================= CSR build (once per launch; graph is layer-invariant) =================
__global__ void deg_kernel(const int* __restrict__ src, int* __restrict__ deg) {
  int e = blockIdx.x * blockDim.x + threadIdx.x;
  if (e >= N_EDGE) return;
  atomicAdd(&deg[src[e]], 1);
}

__global__ __launch_bounds__(1024) void scan1_kernel(const int* __restrict__ deg,
                                                     int* __restrict__ exc,
                                                     int* __restrict__ bsum) {
  __shared__ int tmp[1024];
  int tid = threadIdx.x;
  int i = blockIdx.x * 1024 + tid;
  int v = (i < N_ENT) ? deg[i] : 0;
  tmp[tid] = v;
  __syncthreads();
  for (int off = 1; off < 1024; off <<= 1) {
    int t = (tid >= off) ? tmp[tid - off] : 0;
    __syncthreads();
    tmp[tid] += t;
    __syncthreads();
  }
  if (i < N_ENT) exc[i] = tmp[tid] - v;
  if (tid == 1023) bsum[blockIdx.x] = tmp[1023];
}

__global__ void scan2_kernel(const int* __restrict__ bsum, int* __restrict__ boff) {
  int t = threadIdx.x;  // 64 threads
  int v = (t < NBLK) ? bsum[t] : 0;
  int incl = v;
#pragma unroll
  for (int off = 1; off < 64; off <<= 1) {
    int u = __shfl_up(incl, off);
    if (t >= off) incl += u;
  }
  if (t < NBLK) boff[t] = incl - v;
  if (t == NBLK - 1) boff[NBLK] = incl;
}

__global__ __launch_bounds__(1024) void scan3_kernel(const int* __restrict__ exc,
                                                     const int* __restrict__ boff,
                                                     int* __restrict__ rowptr) {
  int i = blockIdx.x * 1024 + threadIdx.x;
  if (i < N_ENT) rowptr[i] = exc[i] + boff[i >> 10];
  if (i == N_ENT) rowptr[N_ENT] = boff[NBLK];
}

// scatter: csr_src/csr_dst/csr_et in CSR position order
__global__ void scatter_kernel(const int* __restrict__ src, const int* __restrict__ dst,
                               const int* __restrict__ et, int* __restrict__ cursor,
                               int* __restrict__ csr_src, int* __restrict__ csr_dst,
                               int* __restrict__ csr_et) {
  int e = blockIdx.x * blockDim.x + threadIdx.x;
  if (e >= N_EDGE) return;
  int s = src[e];
  int p = atomicAdd(&cursor[s], 1);
  csr_src[p] = s;
  csr_dst[p] = dst[e];
  csr_et[p] = et[e];
}

// ================= LayerNorm: one wave per node; writes f32 h and bf16 h_bf =================
__global__ void ln_kernel(const float* __restrict__ x, const float* __restrict__ g,
                          const float* __restrict__ b, float* __restrict__ h,
                          unsigned short* __restrict__ h_bf) {
  int wid = (blockIdx.x * blockDim.x + threadIdx.x) >> 6;
  int lane = threadIdx.x & 63;
  if (wid >= N_ENT) return;
  float v = x[wid * 64 + lane];
  float s = v;
#pragma unroll
  for (int off = 32; off; off >>= 1) s += __shfl_xor(s, off);
  float mu = s * (1.0f / 64.0f);
  float d = v - mu;
  float s2 = d * d;
#pragma unroll
  for (int off = 32; off; off >>= 1) s2 += __shfl_xor(s2, off);
  float rs = rsqrtf(s2 * (1.0f / 64.0f) + LN_EPS);
  float hv = d * rs * g[lane] + b[lane];
  h[wid * 64 + lane] = hv;
  h_bf[wid * 64 + lane] = (unsigned short)bf16_rne(hv);
}

// ================= node scores: W staged in LDS as float2 pairs; 2 nodes per wave =================
// WP[k][j] = {W[k][j], W[k][j+64]}; lane = col j; x rows via readfirstlane s_load.
__global__ __launch_bounds__(256) void scores_kernel(
    const float* __restrict__ x, const float* __restrict__ W,
    const float* __restrict__ att, float* __restrict__ s_out, int M) {
  __shared__ float2 WP[64][64];
  for (int i = threadIdx.x; i < 64 * 64; i += 256) {
    int k = i >> 6, j = i & 63;
    WP[k][j] = make_float2(W[k * 128 + j], W[k * 128 + j + 64]);
  }
  __syncthreads();
  int lane = threadIdx.x & 63;
  float a0v = att[lane], a1v = att[lane + 64];
  int gw = (blockIdx.x * 256 + threadIdx.x) >> 6;
  int nw = (gridDim.x * 256) >> 6;
  // M is even (50000 / 500) -> n0+1 always valid
  for (int n0 = 2 * gw; n0 < M; n0 += 2 * nw) {
    int nu = __builtin_amdgcn_readfirstlane(n0);
    const float* xr0 = x + nu * 64;
    const float* xr1 = x + (nu + 1) * 64;
    float a00 = 0.f, a01 = 0.f, a10 = 0.f, a11 = 0.f;
#pragma unroll 16
    for (int k = 0; k < 64; ++k) {
      float2 wv = WP[k][lane];
      float xa = xr0[k], xb = xr1[k];
      a00 += xa * wv.x;
      a01 += xa * wv.y;
      a10 += xb * wv.x;
      a11 += xb * wv.y;
    }
    float t00 = tanhf(a00) * a0v, t01 = tanhf(a01) * a1v;
    float t10 = tanhf(a10) * a0v, t11 = tanhf(a11) * a1v;
#pragma unroll
    for (int off = 32; off; off >>= 1) {
      t00 += __shfl_xor(t00, off);
      t01 += __shfl_xor(t01, off);
      t10 += __shfl_xor(t10, off);
      t11 += __shfl_xor(t11, off);
    }
    if (lane == 0) {
      ((float2*)s_out)[nu] = make_float2(t00, t01);
      ((float2*)s_out)[nu + 1] = make_float2(t10, t11);
    }
  }
}

// ================= edge weights: per CSR position (coalesced) =================
__global__ void edge_w_kernel(const int* __restrict__ csr_src, const int* __restrict__ csr_dst,
                              const int* __restrict__ csr_et, const float* __restrict__ s_h,
                              const float* __restrict__ s_t, const float* __restrict__ s_r,
                              float* __restrict__ csr_w) {
  int p = blockIdx.x * blockDim.x + threadIdx.x;
  if (p >= N_EDGE) return;
  int s = csr_src[p], d = csr_dst[p], r = csr_et[p];
  float2 a = ((const float2*)s_h)[s];
  float2 b = ((const float2*)s_t)[d];
  float2 c = ((const float2*)s_r)[r];
  float sc0 = a.x + b.x + c.x;
  float sc1 = a.y + b.y + c.y;
  sc0 = (sc0 >= 0.f) ? sc0 : 0.01f * sc0;
  sc1 = (sc1 >= 0.f) ? sc1 : 0.01f * sc1;
  ((float2*)csr_w)[p] = make_float2(expf(sc0), expf(sc1));
}

// ================= cinv: wave per node, segmented sum over contiguous csr_w =================
__global__ __launch_bounds__(256) void cinv_kernel(const int* __restrict__ rowptr,
                                                   const float* __restrict__ csr_w,
                                                   float* __restrict__ cinv) {
  int n = (blockIdx.x * 256 + threadIdx.x) >> 6;
  int lane = threadIdx.x & 63;
  if (n >= N_ENT) return;
  int p0 = rowptr[n], p1 = rowptr[n + 1];
  float z0 = 0.f, z1 = 0.f;
  for (int p = p0 + lane; p < p1; p += 64) {
    float2 w2 = ((const float2*)csr_w)[p];
    z0 += w2.x;
    z1 += w2.y;
  }
#pragma unroll
  for (int off = 32; off; off >>= 1) {
    z0 += __shfl_xor(z0, off);
    z1 += __shfl_xor(z1, off);
  }
  if (lane == 0) {
    float c0 = (p1 > p0) ? (1.0f - ALPHA) / z0 : 0.f;
    float c1 = (p1 > p0) ? (1.0f - ALPHA) / z1 : 0.f;
    ((float2*)cinv)[n] = make_float2(c0, c1);
  }
}

// ================= monolithic CSR SpMM: wave per node; 4 edge slots x 8 dims/lane =================
template <int IN_H>
__global__ __launch_bounds__(256) void spmm_kernel(
    const int* __restrict__ rowptr, const int* __restrict__ csr_dst,
    const float* __restrict__ csr_w, const float* __restrict__ cinv,
    const float* __restrict__ h, const unsigned short* __restrict__ Zin_b,
    unsigned short* __restrict__ Zout_b) {
  int lane = threadIdx.x & 63;
  int slot = lane >> 4;
  int l16 = lane & 15;
  int hh = l16 >> 3;
  int hoff = 8 * (l16 & 7);
  int gw = (blockIdx.x * 256 + threadIdx.x) >> 6;
  int nw = (gridDim.x * 256) >> 6;
  for (int n = gw; n < N_ENT; n += nw) {
    int p0 = rowptr[n], p1 = rowptr[n + 1];
    float acc[8];
#pragma unroll
    for (int j = 0; j < 8; ++j) acc[j] = 0.f;
    for (int p = p0 + slot; p < p1; p += 4) {
      int d = csr_dst[p];
      float2 w2 = ((const float2*)csr_w)[p];
      float a = hh ? w2.y : w2.x;
      uv4 q;
      if (IN_H) {
        q = *(const uv4*)(Zin_b + d * 64 + hoff);
      } else {
        q = *(const uv4*)(Zin_b + d * 128 + 8 * l16);
      }
      acc[0] += a * __uint_as_float(q.x << 16);
      acc[1] += a * __uint_as_float(q.x & 0xFFFF0000u);
      acc[2] += a * __uint_as_float(q.y << 16);
      acc[3] += a * __uint_as_float(q.y & 0xFFFF0000u);
      acc[4] += a * __uint_as_float(q.z << 16);
      acc[5] += a * __uint_as_float(q.z & 0xFFFF0000u);
      acc[6] += a * __uint_as_float(q.w << 16);
      acc[7] += a * __uint_as_float(q.w & 0xFFFF0000u);
    }
#pragma unroll
    for (int j = 0; j < 8; ++j) {
      acc[j] += __shfl_xor(acc[j], 16);
      acc[j] += __shfl_xor(acc[j], 32);
    }
    if (slot == 0) {
      float c = cinv[n * 2 + hh];
      const float* hp = h + n * 64 + hoff;
      float o[8];
#pragma unroll
      for (int j = 0; j < 8; ++j) o[j] = ALPHA * hp[j] + c * acc[j];
      uv4 qo;
      qo.x = bf16_rne(o[0]) | (bf16_rne(o[1]) << 16);
      qo.y = bf16_rne(o[2]) | (bf16_rne(o[3]) << 16);
      qo.z = bf16_rne(o[4]) | (bf16_rne(o[5]) << 16);
      qo.w = bf16_rne(o[6]) | (bf16_rne(o[7]) << 16);
      *(uv4*)(Zout_b + n * 128 + 8 * l16) = qo;
    }
  }
}

// ================= output: W_o staged in LDS [128][64]; lane = col j =================
// Z row = 16 wave-uniform uv4 loads; per c: ds_read_b32 (2-way alias, free) + FMA.
__global__ __launch_bounds__(256) void out_kernel(
    const unsigned short* __restrict__ Zb, const float* __restrict__ Wo,
    const float* __restrict__ x, float* __restrict__ out) {
  __shared__ float Wos[128][64];
  for (int i = threadIdx.x; i < 128 * 64; i += 256) ((float*)Wos)[i] = Wo[i];
  __syncthreads();
  int lane = threadIdx.x & 63;
  int gw = (blockIdx.x * 256 + threadIdx.x) >> 6;
  int nw = (gridDim.x * 256) >> 6;
  for (int n = gw; n < N_ENT; n += nw) {
    const uv4* zr = (const uv4*)(Zb + (size_t)n * 128);  // 128 bf16 = 16 uv4
    float acc = 0.f;
#pragma unroll
    for (int i = 0; i < 16; ++i) {
      uv4 q = zr[i];
      acc += __uint_as_float(q.x << 16) * Wos[8 * i + 0][lane];
      acc += __uint_as_float(q.x & 0xFFFF0000u) * Wos[8 * i + 1][lane];
      acc += __uint_as_float(q.y << 16) * Wos[8 * i + 2][lane];
      acc += __uint_as_float(q.y & 0xFFFF0000u) * Wos[8 * i + 3][lane];
      acc += __uint_as_float(q.z << 16) * Wos[8 * i + 4][lane];
      acc += __uint_as_float(q.z & 0xFFFF0000u) * Wos[8 * i + 5][lane];
      acc += __uint_as_float(q.w << 16) * Wos[8 * i + 6][lane];
      acc += __uint_as_float(q.w & 0xFFFF0000u) * Wos[8 * i + 7][lane];
    }
    out[n * 64 + lane] = acc + x[n * 64 + lane];
  }
}

extern "C" void kernel_launch(void* const* d_in, const int* in_sizes, int n_in,
                              void* d_out, int out_size, void* d_ws, size_t ws_size,
                              hipStream_t stream) {
  const float* ent0 = (const float*)d_in[0];
  const float* rel  = (const float*)d_in[1];
  const int* eidx   = (const int*)d_in[2];
  const int* src    = eidx;
  const int* dst    = eidx + N_EDGE;
  const int* et     = (const int*)d_in[3];
  const float* gam  = (const float*)d_in[4];
  const float* bet  = (const float*)d_in[5];
  const float* W_h  = (const float*)d_in[6];
  const float* W_t  = (const float*)d_in[7];
  const float* W_r  = (const float*)d_in[8];
  const float* att_h = (const float*)d_in[9];
  const float* att_t = (const float*)d_in[10];
  const float* att_r = (const float*)d_in[11];
  const float* W_o  = (const float*)d_in[12];
  float* outp = (float*)d_out;

  char* w = (char*)d_ws;
  auto alloc = [&](size_t bytes) {
    char* p = w;
    w += (bytes + 255) & ~(size_t)255;
    return p;
  };
  float* ent1   = (float*)alloc((size_t)N_ENT * 64 * 4);
  float* h      = (float*)alloc((size_t)N_ENT * 64 * 4);
  unsigned short* h_bf = (unsigned short*)alloc((size_t)N_ENT * 64 * 2);
  float* s_h    = (float*)alloc((size_t)N_ENT * 2 * 4);
  float* s_t    = (float*)alloc((size_t)N_ENT * 2 * 4);
  float* s_r    = (float*)alloc((size_t)N_REL * 2 * 4);
  float* cinv   = (float*)alloc((size_t)N_ENT * 2 * 4);
  float* csr_w  = (float*)alloc((size_t)N_EDGE * 2 * 4);
  unsigned short* Zb0 = (unsigned short*)alloc((size_t)N_ENT * 128 * 2);
  unsigned short* Zb1 = (unsigned short*)alloc((size_t)N_ENT * 128 * 2);
  int* deg      = (int*)alloc((size_t)N_ENT * 4);
  int* exc      = (int*)alloc((size_t)N_ENT * 4);
  int* bsum     = (int*)alloc((size_t)NBLK * 4);
  int* boff     = (int*)alloc((size_t)(NBLK + 1) * 4);
  int* rowptr   = (int*)alloc((size_t)(N_ENT + 1) * 4);
  int* cursor   = (int*)alloc((size_t)N_ENT * 4);
  int* csr_src  = (int*)alloc((size_t)N_EDGE * 4);
  int* csr_dst  = (int*)alloc((size_t)N_EDGE * 4);
  int* csr_et   = (int*)alloc((size_t)N_EDGE * 4);

  const int EB = (N_EDGE + 255) / 256;

  // ---- CSR build ----
  hipMemsetAsync(deg, 0, (size_t)N_ENT * 4, stream);
  deg_kernel<<<EB, 256, 0, stream>>>(src, deg);
  scan1_kernel<<<NBLK, 1024, 0, stream>>>(deg, exc, bsum);
  scan2_kernel<<<1, 64, 0, stream>>>(bsum, boff);
  scan3_kernel<<<NBLK, 1024, 0, stream>>>(exc, boff, rowptr);
  hipMemcpyAsync(cursor, rowptr, (size_t)N_ENT * 4, hipMemcpyDeviceToDevice, stream);
  scatter_kernel<<<EB, 256, 0, stream>>>(src, dst, et, cursor, csr_src, csr_dst, csr_et);

  for (int l = 0; l < 2; ++l) {
    const float* x = (l == 0) ? ent0 : ent1;
    float* y = (l == 0) ? ent1 : outp;

    ln_kernel<<<(N_ENT + 3) / 4, 256, 0, stream>>>(x, gam + l * 64, bet + l * 64, h, h_bf);
    scores_kernel<<<512, 256, 0, stream>>>(h, W_h + l * 8192, att_h + l * 128, s_h, N_ENT);
    scores_kernel<<<512, 256, 0, stream>>>(h, W_t + l * 8192, att_t + l * 128, s_t, N_ENT);
    scores_kernel<<<8, 256, 0, stream>>>(rel, W_r + l * 8192, att_r + l * 128, s_r, N_REL);

    edge_w_kernel<<<EB, 256, 0, stream>>>(csr_src, csr_dst, csr_et, s_h, s_t, s_r, csr_w);
    cinv_kernel<<<(N_ENT * 64 + 255) / 256, 256, 0, stream>>>(rowptr, csr_w, cinv);

    // ---- PPR power iteration: h_bf -> Zb0 -> Zb1 -> Zb0 (all bf16) ----
    spmm_kernel<1><<<2048, 256, 0, stream>>>(rowptr, csr_dst, csr_w, cinv, h, h_bf, Zb0);
    spmm_kernel<0><<<2048, 256, 0, stream>>>(rowptr, csr_dst, csr_w, cinv, h, Zb0, Zb1);
    spmm_kernel<0><<<2048, 256, 0, stream>>>(rowptr, csr_dst, csr_w, cinv, h, Zb1, Zb0);

    out_kernel<<<512, 256, 0, stream>>>(Zb0, W_o + l * 8192, x, y);
  }
}